// Round 5
// baseline (595.930 us; speedup 1.0000x reference)
//
#include <hip/hip_runtime.h>
#include <hip/hip_bf16.h>
#include <cstdint>
#include <cstddef>

#define M_ROWS 16384   // B*N
#define CDIM   512
#define HEADS  8
#define HD     64
#define NSEQ   1024
#define BATCH  16
#define NPART  256     // deterministic stats partial rows per branch

// ---------------------------------------------------------------------------
// GEMM: C[m,n] = sum_k A[m,k] * W[n,k]   (A:[M,K] row-major, W:[N,K] row-major)
// 128x128 tile, BK=16, 256 threads, 8x8 microtile -> 64 FMA per 4 ds_read_b128
// per k-step (VALU-bound by design; f32 has no MFMA path on CDNA4).
// blockIdx.z selects among three (W, C) pairs so one launch does q,k,v.
// ---------------------------------------------------------------------------
#define BM 128
#define BN 128
#define BK 16

__global__ __launch_bounds__(256, 2) void gemm_nt(
    const float* __restrict__ A,
    const float* __restrict__ W0, const float* __restrict__ W1, const float* __restrict__ W2,
    float* __restrict__ C0, float* __restrict__ C1, float* __restrict__ C2,
    int K, int ldc)
{
  const float* W = (blockIdx.z == 0) ? W0 : (blockIdx.z == 1) ? W1 : W2;
  float* Cm      = (blockIdx.z == 0) ? C0 : (blockIdx.z == 1) ? C1 : C2;

  __shared__ float As[BK][BM + 4];   // transposed tiles; +4 pad -> stores 2-way (free)
  __shared__ float Bs[BK][BN + 4];

  const int tid = threadIdx.x;
  const int bm = blockIdx.y * BM;
  const int bn = blockIdx.x * BN;
  const int tx = tid & 15;        // col group: owns cols tx*4..+3 and 64+tx*4..+3
  const int ty = tid >> 4;        // row group: owns rows ty*8..+7

  float acc[8][8];
  #pragma unroll
  for (int i = 0; i < 8; ++i)
    #pragma unroll
    for (int j = 0; j < 8; ++j) acc[i][j] = 0.f;

  for (int k0 = 0; k0 < K; k0 += BK) {
    // A tile: 128x16 = 512 float4, 2 per thread; stored transposed As[k][row].
    #pragma unroll
    for (int i = 0; i < 2; ++i) {
      int f = tid + i * 256;
      int row = f >> 2, kq = f & 3;
      const float4 v = *(const float4*)(A + (size_t)(bm + row) * K + k0 + kq * 4);
      As[kq * 4 + 0][row] = v.x;
      As[kq * 4 + 1][row] = v.y;
      As[kq * 4 + 2][row] = v.z;
      As[kq * 4 + 3][row] = v.w;
    }
    #pragma unroll
    for (int i = 0; i < 2; ++i) {
      int f = tid + i * 256;
      int row = f >> 2, kq = f & 3;
      const float4 v = *(const float4*)(W + (size_t)(bn + row) * K + k0 + kq * 4);
      Bs[kq * 4 + 0][row] = v.x;
      Bs[kq * 4 + 1][row] = v.y;
      Bs[kq * 4 + 2][row] = v.z;
      Bs[kq * 4 + 3][row] = v.w;
    }
    __syncthreads();

    #pragma unroll
    for (int kk = 0; kk < BK; ++kk) {
      // A reads: 4 addrs/wave (16-lane broadcast). B reads: 16 addrs spanning
      // 64 floats -> 2-way bank wrap (free per m136).
      const float4 a0 = *(const float4*)&As[kk][ty * 8];
      const float4 a1 = *(const float4*)&As[kk][ty * 8 + 4];
      const float4 b0 = *(const float4*)&Bs[kk][tx * 4];
      const float4 b1 = *(const float4*)&Bs[kk][64 + tx * 4];
      const float a[8] = {a0.x, a0.y, a0.z, a0.w, a1.x, a1.y, a1.z, a1.w};
      const float b[8] = {b0.x, b0.y, b0.z, b0.w, b1.x, b1.y, b1.z, b1.w};
      #pragma unroll
      for (int i = 0; i < 8; ++i)
        #pragma unroll
        for (int j = 0; j < 8; ++j)
          acc[i][j] = fmaf(a[i], b[j], acc[i][j]);
    }
    __syncthreads();
  }

  // C write: per instruction, 16 lanes cover 64 consecutive cols (256B contig).
  #pragma unroll
  for (int i = 0; i < 8; ++i) {
    float* crow = Cm + (size_t)(bm + ty * 8 + i) * ldc + bn;
    *(float4*)(crow + tx * 4)      = make_float4(acc[i][0], acc[i][1], acc[i][2], acc[i][3]);
    *(float4*)(crow + 64 + tx * 4) = make_float4(acc[i][4], acc[i][5], acc[i][6], acc[i][7]);
  }
}

// ---------------------------------------------------------------------------
// Deterministic batch stats, stage A: per-chunk per-channel (sum, sumsq).
// grid (NPART/2 chunks of 128 rows, 3 branches), block 256; sub = t>>7 halves
// the chunk -> NPART fixed partial rows per branch. No atomics -> replay-stable.
// Relies on yq/yk/yv being contiguous (single ws allocation).
// ---------------------------------------------------------------------------
__global__ __launch_bounds__(256) void stats_partial(const float* __restrict__ y,
                                                     float* __restrict__ partial)
{
  const int branch = blockIdx.y;
  const int chunk = blockIdx.x;
  const int t = threadIdx.x;
  const int sub = t >> 7;          // 0/1: rows [0,64) / [64,128) of the chunk
  const int c4 = t & 127;          // channel group: c4*4 .. c4*4+3
  const float* yb = y + (size_t)branch * M_ROWS * CDIM
                      + (size_t)(chunk * 128 + sub * 64) * CDIM + c4 * 4;

  float s[4] = {0.f, 0.f, 0.f, 0.f}, q[4] = {0.f, 0.f, 0.f, 0.f};
  for (int r = 0; r < 64; ++r) {
    float4 v = *(const float4*)(yb + (size_t)r * CDIM);
    s[0] += v.x; q[0] += v.x * v.x;
    s[1] += v.y; q[1] += v.y * v.y;
    s[2] += v.z; q[2] += v.z * v.z;
    s[3] += v.w; q[3] += v.w * v.w;
  }
  const int pr = chunk * 2 + sub;  // [0, NPART)
  float2* pb = (float2*)partial + ((size_t)branch * NPART + pr) * CDIM + c4 * 4;
  #pragma unroll
  for (int j = 0; j < 4; ++j) pb[j] = make_float2(s[j], q[j]);
}

// ---------------------------------------------------------------------------
// Stage B + affine: sequentially (deterministically) fold NPART partials per
// channel, then ab = (gamma*rsig, beta - gamma*mean*rsig) so spike is y*a+b>1.
// ---------------------------------------------------------------------------
__global__ void finalize_stats(const float* __restrict__ partial, float* __restrict__ ab,
                               const float* __restrict__ g0, const float* __restrict__ b0,
                               const float* __restrict__ g1, const float* __restrict__ b1,
                               const float* __restrict__ g2, const float* __restrict__ b2)
{
  const int branch = blockIdx.x;
  const int c = threadIdx.x;  // 512
  const float* g  = branch == 0 ? g0 : branch == 1 ? g1 : g2;
  const float* be = branch == 0 ? b0 : branch == 1 ? b1 : b2;

  float sum = 0.f, sq = 0.f;
  const float2* pb = (const float2*)partial + (size_t)branch * NPART * CDIM + c;
  for (int pr = 0; pr < NPART; ++pr) {
    float2 v = pb[(size_t)pr * CDIM];
    sum += v.x; sq += v.y;
  }
  const float invn = 1.f / (float)M_ROWS;
  float mean = sum * invn;
  float var  = sq * invn - mean * mean;   // biased variance (matches reference)
  float rsig = rsqrtf(var + 1e-5f);
  ((float2*)ab)[branch * CDIM + c] = make_float2(g[c] * rsig, be[c] - g[c] * mean * rsig);
}

// ---------------------------------------------------------------------------
// KV[b,h,d',d] = sum_m spike_k[b,m,h,d'] * spike_v[b,m,h,d]; spikes computed
// inline from raw GEMM output (saves a 200MB spike pass). Partial sums are
// exact small integers in f32 -> atomicAdd is order-independent/deterministic.
// grid (NSEQ/64, H, B), block 256.
// ---------------------------------------------------------------------------
__global__ __launch_bounds__(256) void kv_kernel(const float* __restrict__ kraw,
                                                 const float* __restrict__ vraw,
                                                 const float* __restrict__ ab,
                                                 float* __restrict__ KV)
{
  const int b = blockIdx.z, h = blockIdx.y, mc = blockIdx.x;
  __shared__ float ks[64][64];
  __shared__ float vs[64][64];
  __shared__ float ka_s[64], kb_s[64], va_s[64], vb_s[64];
  const int t = threadIdx.x;

  if (t < 64) {
    float2 kab = ((const float2*)ab)[1 * CDIM + h * HD + t];
    ka_s[t] = kab.x; kb_s[t] = kab.y;
  } else if (t < 128) {
    int j = t - 64;
    float2 vab = ((const float2*)ab)[2 * CDIM + h * HD + j];
    va_s[j] = vab.x; vb_s[j] = vab.y;
  }
  __syncthreads();

  const size_t base = ((size_t)(b * NSEQ + mc * 64)) * CDIM + h * HD;
  #pragma unroll
  for (int i = 0; i < 4; ++i) {
    int f = t + i * 256;          // 1024 float4 per matrix
    int row = f >> 4, c4 = f & 15;
    float4 kv4 = *(const float4*)(kraw + base + (size_t)row * CDIM + c4 * 4);
    float4 vv4 = *(const float4*)(vraw + base + (size_t)row * CDIM + c4 * 4);
    int c = c4 * 4;
    kv4.x = (kv4.x * ka_s[c+0] + kb_s[c+0] > 1.0f) ? 1.f : 0.f;
    kv4.y = (kv4.y * ka_s[c+1] + kb_s[c+1] > 1.0f) ? 1.f : 0.f;
    kv4.z = (kv4.z * ka_s[c+2] + kb_s[c+2] > 1.0f) ? 1.f : 0.f;
    kv4.w = (kv4.w * ka_s[c+3] + kb_s[c+3] > 1.0f) ? 1.f : 0.f;
    vv4.x = (vv4.x * va_s[c+0] + vb_s[c+0] > 1.0f) ? 1.f : 0.f;
    vv4.y = (vv4.y * va_s[c+1] + vb_s[c+1] > 1.0f) ? 1.f : 0.f;
    vv4.z = (vv4.z * va_s[c+2] + vb_s[c+2] > 1.0f) ? 1.f : 0.f;
    vv4.w = (vv4.w * va_s[c+3] + vb_s[c+3] > 1.0f) ? 1.f : 0.f;
    *(float4*)&ks[row][c4 * 4] = kv4;
    *(float4*)&vs[row][c4 * 4] = vv4;
  }
  __syncthreads();

  const int d = t & 63;           // lane-consecutive -> 2-way LDS wrap (free)
  const int dp0 = (t >> 6) * 16;  // 16 d' per thread
  float acc[16];
  #pragma unroll
  for (int j = 0; j < 16; ++j) acc[j] = 0.f;

  for (int m = 0; m < 64; ++m) {
    float vv = vs[m][d];
    #pragma unroll
    for (int q4 = 0; q4 < 4; ++q4) {
      float4 kf = *(const float4*)&ks[m][dp0 + q4 * 4];   // broadcast across wave
      acc[q4 * 4 + 0] = fmaf(kf.x, vv, acc[q4 * 4 + 0]);
      acc[q4 * 4 + 1] = fmaf(kf.y, vv, acc[q4 * 4 + 1]);
      acc[q4 * 4 + 2] = fmaf(kf.z, vv, acc[q4 * 4 + 2]);
      acc[q4 * 4 + 3] = fmaf(kf.w, vv, acc[q4 * 4 + 3]);
    }
  }
  float* kvb = KV + ((size_t)(b * HEADS + h)) * HD * HD;
  #pragma unroll
  for (int j = 0; j < 16; ++j)
    atomicAdd(&kvb[(dp0 + j) * HD + d], acc[j]);
}

// ---------------------------------------------------------------------------
// out1[b,n,h*64+d] = SCALE * sum_d' spike_q[b,n,h,d'] * KV[b,h,d',d]
// grid (NSEQ/128, H, B), block 256. Spike applied inline on q during staging.
// ---------------------------------------------------------------------------
__global__ __launch_bounds__(256) void qkv_kernel(const float* __restrict__ qraw,
                                                  const float* __restrict__ ab,
                                                  const float* __restrict__ KV,
                                                  float* __restrict__ out1)
{
  const int b = blockIdx.z, h = blockIdx.y, rc = blockIdx.x;
  __shared__ float kvs[64][64];
  __shared__ float qs[128][64];
  __shared__ float qa_s[64], qb_s[64];
  const int t = threadIdx.x;

  if (t < 64) {
    float2 qab = ((const float2*)ab)[0 * CDIM + h * HD + t];
    qa_s[t] = qab.x; qb_s[t] = qab.y;
  }
  __syncthreads();

  const float* kvb = KV + ((size_t)(b * HEADS + h)) * HD * HD;
  #pragma unroll
  for (int i = 0; i < 4; ++i) {
    int f = t + i * 256;          // 1024 float4
    int row = f >> 4, c4 = f & 15;
    *(float4*)&kvs[row][c4 * 4] = *(const float4*)(kvb + row * 64 + c4 * 4);
  }
  const size_t qbase = ((size_t)(b * NSEQ + rc * 128)) * CDIM + h * HD;
  #pragma unroll
  for (int i = 0; i < 8; ++i) {
    int f = t + i * 256;          // 2048 float4
    int row = f >> 4, c4 = f & 15;
    float4 v = *(const float4*)(qraw + qbase + (size_t)row * CDIM + c4 * 4);
    int c = c4 * 4;
    v.x = (v.x * qa_s[c+0] + qb_s[c+0] > 1.0f) ? 1.f : 0.f;
    v.y = (v.y * qa_s[c+1] + qb_s[c+1] > 1.0f) ? 1.f : 0.f;
    v.z = (v.z * qa_s[c+2] + qb_s[c+2] > 1.0f) ? 1.f : 0.f;
    v.w = (v.w * qa_s[c+3] + qb_s[c+3] > 1.0f) ? 1.f : 0.f;
    *(float4*)&qs[row][c4 * 4] = v;
  }
  __syncthreads();

  const int d = t & 63;
  const int rg = t >> 6;
  for (int r = rg * 32; r < rg * 32 + 32; ++r) {
    float acc = 0.f;
    #pragma unroll
    for (int dq = 0; dq < 16; ++dq) {
      float4 qf = *(const float4*)&qs[r][dq * 4];   // broadcast across wave
      acc = fmaf(qf.x, kvs[dq * 4 + 0][d], acc);
      acc = fmaf(qf.y, kvs[dq * 4 + 1][d], acc);
      acc = fmaf(qf.z, kvs[dq * 4 + 2][d], acc);
      acc = fmaf(qf.w, kvs[dq * 4 + 3][d], acc);
    }
    out1[((size_t)(b * NSEQ + rc * 128 + r)) * CDIM + h * HD + d] = acc * 0.125f;
  }
}

// ---------------------------------------------------------------------------
extern "C" void kernel_launch(void* const* d_in, const int* in_sizes, int n_in,
                              void* d_out, int out_size, void* d_ws, size_t ws_size,
                              hipStream_t stream)
{
  const float* x  = (const float*)d_in[0];
  const float* Wq = (const float*)d_in[1];
  const float* Wk = (const float*)d_in[2];
  const float* Wv = (const float*)d_in[3];
  const float* Wo = (const float*)d_in[4];
  const float* qg = (const float*)d_in[5];
  const float* qb = (const float*)d_in[6];
  const float* kg = (const float*)d_in[7];
  const float* kb = (const float*)d_in[8];
  const float* vg = (const float*)d_in[9];
  const float* vb = (const float*)d_in[10];
  float* out = (float*)d_out;

  char* ws = (char*)d_ws;
  const size_t ybytes  = (size_t)M_ROWS * CDIM * sizeof(float);            // 33.55 MB
  const size_t pbytes  = (size_t)3 * NPART * CDIM * 2 * sizeof(float);     // 3.15 MB
  const size_t abbytes = (size_t)3 * CDIM * 2 * sizeof(float);
  const size_t kvbytes = (size_t)BATCH * HEADS * HD * HD * sizeof(float);  // 2.10 MB
  const size_t need = 3 * ybytes + pbytes + abbytes + kvbytes;             // ~106 MB

  // ws overflow guard: if scratch is too small, skip (harness reports
  // "incorrect" instead of faulting the container). ws_size is call-invariant,
  // so this branch is graph-capture-safe.
  if (ws_size < need) return;

  float* yq      = (float*)(ws);
  float* yk      = (float*)(ws + ybytes);
  float* yv      = (float*)(ws + 2 * ybytes);
  float* partial = (float*)(ws + 3 * ybytes);
  float* ab      = (float*)(ws + 3 * ybytes + pbytes);
  float* KV      = (float*)(ws + 3 * ybytes + pbytes + abbytes);
  float* out1    = yk;  // safe reuse: k consumed by kv_kernel before qkv writes

  // zero the (exact-integer) atomic accumulator; ws is re-poisoned every call
  hipMemsetAsync(KV, 0, kvbytes, stream);

  // 1) y{q,k,v} = x @ W{q,k,v}.T   (raw, pre-BN)
  gemm_nt<<<dim3(CDIM / BN, M_ROWS / BM, 3), 256, 0, stream>>>(
      x, Wq, Wk, Wv, yq, yk, yv, CDIM, CDIM);

  // 2) deterministic per-channel batch stats (two-stage, no float atomics)
  stats_partial<<<dim3(NPART / 2, 3), 256, 0, stream>>>(yq, partial);
  finalize_stats<<<3, CDIM, 0, stream>>>(partial, ab, qg, qb, kg, kb, vg, vb);

  // 3) KV = spike(k)^T spike(v) per (b,h), spikes inline
  kv_kernel<<<dim3(NSEQ / 64, HEADS, BATCH), 256, 0, stream>>>(yk, yv, ab, KV);

  // 4) out1 = scale * spike(q) @ KV, spike inline
  qkv_kernel<<<dim3(NSEQ / 128, HEADS, BATCH), 256, 0, stream>>>(yq, ab, KV, out1);

  // 5) out = out1 @ Wo.T
  gemm_nt<<<dim3(CDIM / BN, M_ROWS / BM, 1), 256, 0, stream>>>(
      out1, Wo, Wo, Wo, out, out, out, CDIM, CDIM);
}

// Round 8
// 378.868 us; speedup vs baseline: 1.5729x; 1.5729x over previous
//
#include <hip/hip_runtime.h>
#include <hip/hip_bf16.h>
#include <cstdint>
#include <cstddef>

#define M_ROWS 16384   // B*N
#define CDIM   512
#define HEADS  8
#define HD     64
#define NSEQ   1024
#define BATCH  16
#define NPART  256     // deterministic stats partial rows per branch

typedef _Float16 h8 __attribute__((ext_vector_type(8)));
typedef float f4 __attribute__((ext_vector_type(4)));

// Split one f32 into fp16 hi + fp16 lo*2^11 (classic 2-term split; lo pre-scaled
// so it stays in fp16 normal range -> MFMA denorm flush is harmless).
__device__ __forceinline__ void split8(float4 u, float4 v, h8& hi, h8& lo) {
  float t[8] = {u.x, u.y, u.z, u.w, v.x, v.y, v.z, v.w};
  #pragma unroll
  for (int e = 0; e < 8; ++e) {
    _Float16 h = (_Float16)t[e];
    hi[e] = h;
    lo[e] = (_Float16)((t[e] - (float)h) * 2048.0f);
  }
}

// ---------------------------------------------------------------------------
// MFMA GEMM: C[m,n] = sum_k A[m,k]*W[n,k] via fp16x2 split precision.
// y = (Ah+Al/2^11)(Wh+Wl/2^11) ~= Ah*Wh + (Ah*Wl2 + Al2*Wh)*2^-11  (3 MFMA)
// 128x128 tile, BK=32, 4 waves of 64x64 (4x4 fragments of 16x16x32).
// Fragment layout: A/B row = lane&15, k = 8*(lane>>4)+e (consecutive-8,
// matches the guide's CPU-refchecked m90-m97 ladder); C/D col=lane&15,
// row=(lane>>4)*4+reg (m89-verified).
// ---------------------------------------------------------------------------
__global__ __launch_bounds__(256, 2) void gemm16(
    const float* __restrict__ A,
    const float* __restrict__ W0, const float* __restrict__ W1, const float* __restrict__ W2,
    float* __restrict__ C0, float* __restrict__ C1, float* __restrict__ C2,
    int K, int ldc)
{
  const float* W = (blockIdx.z == 0) ? W0 : (blockIdx.z == 1) ? W1 : W2;
  float* Cm      = (blockIdx.z == 0) ? C0 : (blockIdx.z == 1) ? C1 : C2;

  __shared__ _Float16 sAh[128][40], sAl[128][40], sBh[128][40], sBl[128][40];

  const int tid = threadIdx.x;
  const int bm = blockIdx.y * 128;
  const int bn = blockIdx.x * 128;
  const int srow = tid >> 1;          // staging row 0..127
  const int skq  = (tid & 1) * 16;    // staging k-offset (floats in, halves out)

  const int ln = tid & 63;
  const int wr = ((tid >> 6) >> 1) * 64;   // wave row base
  const int wc = ((tid >> 6) & 1) * 64;    // wave col base
  const int fr = ln & 15;                  // fragment row/col
  const int fk = (ln >> 4) * 8;            // fragment k offset (halves)

  f4 acc1[4][4], acc2[4][4];
  #pragma unroll
  for (int i = 0; i < 4; ++i)
    #pragma unroll
    for (int j = 0; j < 4; ++j) { acc1[i][j] = 0.f; acc2[i][j] = 0.f; }

  const float* ga = A + (size_t)(bm + srow) * K + skq;
  const float* gb = W + (size_t)(bn + srow) * K + skq;

  // prologue: load K-step 0
  float4 a0 = *(const float4*)(ga + 0),  a1 = *(const float4*)(ga + 4);
  float4 a2 = *(const float4*)(ga + 8),  a3 = *(const float4*)(ga + 12);
  float4 b0 = *(const float4*)(gb + 0),  b1 = *(const float4*)(gb + 4);
  float4 b2 = *(const float4*)(gb + 8),  b3 = *(const float4*)(gb + 12);

  for (int k0 = 0; k0 < K; k0 += 32) {
    h8 hA0, lA0, hA1, lA1, hB0, lB0, hB1, lB1;
    split8(a0, a1, hA0, lA0); split8(a2, a3, hA1, lA1);
    split8(b0, b1, hB0, lB0); split8(b2, b3, hB1, lB1);
    __syncthreads();                      // prior iteration's reads complete
    *(h8*)&sAh[srow][skq] = hA0; *(h8*)&sAh[srow][skq + 8] = hA1;
    *(h8*)&sAl[srow][skq] = lA0; *(h8*)&sAl[srow][skq + 8] = lA1;
    *(h8*)&sBh[srow][skq] = hB0; *(h8*)&sBh[srow][skq + 8] = hB1;
    *(h8*)&sBl[srow][skq] = lB0; *(h8*)&sBl[srow][skq + 8] = lB1;
    __syncthreads();

    if (k0 + 32 < K) {                    // prefetch next K-step under MFMA
      const float* pa = ga + k0 + 32;
      a0 = *(const float4*)(pa + 0);  a1 = *(const float4*)(pa + 4);
      a2 = *(const float4*)(pa + 8);  a3 = *(const float4*)(pa + 12);
      const float* pb = gb + k0 + 32;
      b0 = *(const float4*)(pb + 0);  b1 = *(const float4*)(pb + 4);
      b2 = *(const float4*)(pb + 8);  b3 = *(const float4*)(pb + 12);
    }

    h8 bhf[4], blf[4];
    #pragma unroll
    for (int j = 0; j < 4; ++j) {
      bhf[j] = *(const h8*)&sBh[wc + j * 16 + fr][fk];
      blf[j] = *(const h8*)&sBl[wc + j * 16 + fr][fk];
    }
    #pragma unroll
    for (int i = 0; i < 4; ++i) {
      h8 ah = *(const h8*)&sAh[wr + i * 16 + fr][fk];
      h8 al = *(const h8*)&sAl[wr + i * 16 + fr][fk];
      #pragma unroll
      for (int j = 0; j < 4; ++j) {
        acc1[i][j] = __builtin_amdgcn_mfma_f32_16x16x32_f16(ah, bhf[j], acc1[i][j], 0, 0, 0);
        acc2[i][j] = __builtin_amdgcn_mfma_f32_16x16x32_f16(ah, blf[j], acc2[i][j], 0, 0, 0);
        acc2[i][j] = __builtin_amdgcn_mfma_f32_16x16x32_f16(al, bhf[j], acc2[i][j], 0, 0, 0);
      }
    }
  }

  // C/D layout [m89-verified]: col = lane&15, row = (lane>>4)*4 + reg
  const int orow = (ln >> 4) * 4;
  #pragma unroll
  for (int i = 0; i < 4; ++i)
    #pragma unroll
    for (int j = 0; j < 4; ++j) {
      float* cp = Cm + (size_t)(bm + wr + i * 16 + orow) * ldc + (bn + wc + j * 16 + fr);
      #pragma unroll
      for (int r = 0; r < 4; ++r)
        cp[(size_t)r * ldc] = acc1[i][j][r] + acc2[i][j][r] * 4.8828125e-4f;  // 2^-11
    }
}

// ---------------------------------------------------------------------------
// Deterministic batch stats, stage A — BYTE-IDENTICAL to the passing round
// (same partial layout + fold order keeps bn-stat bits within ~2e-9 drift).
// ---------------------------------------------------------------------------
__global__ __launch_bounds__(256) void stats_partial(const float* __restrict__ y,
                                                     float* __restrict__ partial)
{
  const int branch = blockIdx.y;
  const int chunk = blockIdx.x;
  const int t = threadIdx.x;
  const int sub = t >> 7;          // 0/1: rows [0,64) / [64,128) of the chunk
  const int c4 = t & 127;          // channel group: c4*4 .. c4*4+3
  const float* yb = y + (size_t)branch * M_ROWS * CDIM
                      + (size_t)(chunk * 128 + sub * 64) * CDIM + c4 * 4;

  float s[4] = {0.f, 0.f, 0.f, 0.f}, q[4] = {0.f, 0.f, 0.f, 0.f};
  for (int r = 0; r < 64; ++r) {
    float4 v = *(const float4*)(yb + (size_t)r * CDIM);
    s[0] += v.x; q[0] += v.x * v.x;
    s[1] += v.y; q[1] += v.y * v.y;
    s[2] += v.z; q[2] += v.z * v.z;
    s[3] += v.w; q[3] += v.w * v.w;
  }
  const int pr = chunk * 2 + sub;  // [0, NPART)
  float2* pb = (float2*)partial + ((size_t)branch * NPART + pr) * CDIM + c4 * 4;
  #pragma unroll
  for (int j = 0; j < 4; ++j) pb[j] = make_float2(s[j], q[j]);
}

// ---------------------------------------------------------------------------
// Stage B + affine (unchanged): ab = (gamma*rsig, beta - gamma*mean*rsig).
// ---------------------------------------------------------------------------
__global__ void finalize_stats(const float* __restrict__ partial, float* __restrict__ ab,
                               const float* __restrict__ g0, const float* __restrict__ b0,
                               const float* __restrict__ g1, const float* __restrict__ b1,
                               const float* __restrict__ g2, const float* __restrict__ b2)
{
  const int branch = blockIdx.x;
  const int c = threadIdx.x;  // 512
  const float* g  = branch == 0 ? g0 : branch == 1 ? g1 : g2;
  const float* be = branch == 0 ? b0 : branch == 1 ? b1 : b2;

  float sum = 0.f, sq = 0.f;
  const float2* pb = (const float2*)partial + (size_t)branch * NPART * CDIM + c;
  for (int pr = 0; pr < NPART; ++pr) {
    float2 v = pb[(size_t)pr * CDIM];
    sum += v.x; sq += v.y;
  }
  const float invn = 1.f / (float)M_ROWS;
  float mean = sum * invn;
  float var  = sq * invn - mean * mean;   // biased variance (matches reference)
  float rsig = rsqrtf(var + 1e-5f);
  ((float2*)ab)[branch * CDIM + c] = make_float2(g[c] * rsig, be[c] - g[c] * mean * rsig);
}

// ---------------------------------------------------------------------------
// Exact-spike fixup: any y within 1e-4 of the spike threshold (in bn units;
// fp16x2 GEMM error ~7e-7 << band) is recomputed with the exact f32 serial-k
// fma dot (bit-identical to the round-5 f32 GEMM that passed with absmax=0).
// ~600 of 25M elements take the slow path. Runs AFTER stats, BEFORE kv/qkv.
// ---------------------------------------------------------------------------
__global__ __launch_bounds__(256) void fixup_kernel(
    float* __restrict__ y, const float* __restrict__ ab,
    const float* __restrict__ x,
    const float* __restrict__ Wq, const float* __restrict__ Wk,
    const float* __restrict__ Wv)
{
  const size_t total = (size_t)3 * M_ROWS * CDIM;
  const size_t stride = (size_t)gridDim.x * blockDim.x * 4;
  for (size_t i4 = ((size_t)blockIdx.x * blockDim.x + threadIdx.x) * 4;
       i4 < total; i4 += stride) {
    float4 v = *(const float4*)(y + i4);
    float vv[4] = {v.x, v.y, v.z, v.w};
    const int c0 = (int)(i4 & (CDIM - 1));
    const int branch = (int)(i4 / ((size_t)M_ROWS * CDIM));
    const float2* abb = (const float2*)ab + branch * CDIM;
    #pragma unroll
    for (int u = 0; u < 4; ++u) {
      float2 ab2 = abb[c0 + u];
      float t = vv[u] * ab2.x + ab2.y;
      if (fabsf(t - 1.0f) < 1e-4f) {
        size_t rem = (i4 + u) - (size_t)branch * M_ROWS * CDIM;
        int m = (int)(rem >> 9);       // / CDIM
        int c = (int)(rem & (CDIM - 1));
        const float* Wp = branch == 0 ? Wq : branch == 1 ? Wk : Wv;
        const float* xr = x + (size_t)m * CDIM;
        const float* wrow = Wp + (size_t)c * CDIM;
        float acc = 0.f;
        for (int k = 0; k < CDIM; ++k) acc = fmaf(xr[k], wrow[k], acc);
        y[i4 + u] = acc;               // exact value -> exact spike decision
      }
    }
  }
}

// ---------------------------------------------------------------------------
// KV = spike(k)^T spike(v) per (b,h), spikes inline (unchanged).
// ---------------------------------------------------------------------------
__global__ __launch_bounds__(256) void kv_kernel(const float* __restrict__ kraw,
                                                 const float* __restrict__ vraw,
                                                 const float* __restrict__ ab,
                                                 float* __restrict__ KV)
{
  const int b = blockIdx.z, h = blockIdx.y, mc = blockIdx.x;
  __shared__ float ks[64][64];
  __shared__ float vs[64][64];
  __shared__ float ka_s[64], kb_s[64], va_s[64], vb_s[64];
  const int t = threadIdx.x;

  if (t < 64) {
    float2 kab = ((const float2*)ab)[1 * CDIM + h * HD + t];
    ka_s[t] = kab.x; kb_s[t] = kab.y;
  } else if (t < 128) {
    int j = t - 64;
    float2 vab = ((const float2*)ab)[2 * CDIM + h * HD + j];
    va_s[j] = vab.x; vb_s[j] = vab.y;
  }
  __syncthreads();

  const size_t base = ((size_t)(b * NSEQ + mc * 64)) * CDIM + h * HD;
  #pragma unroll
  for (int i = 0; i < 4; ++i) {
    int f = t + i * 256;          // 1024 float4 per matrix
    int row = f >> 4, c4 = f & 15;
    float4 kv4 = *(const float4*)(kraw + base + (size_t)row * CDIM + c4 * 4);
    float4 vv4 = *(const float4*)(vraw + base + (size_t)row * CDIM + c4 * 4);
    int c = c4 * 4;
    kv4.x = (kv4.x * ka_s[c+0] + kb_s[c+0] > 1.0f) ? 1.f : 0.f;
    kv4.y = (kv4.y * ka_s[c+1] + kb_s[c+1] > 1.0f) ? 1.f : 0.f;
    kv4.z = (kv4.z * ka_s[c+2] + kb_s[c+2] > 1.0f) ? 1.f : 0.f;
    kv4.w = (kv4.w * ka_s[c+3] + kb_s[c+3] > 1.0f) ? 1.f : 0.f;
    vv4.x = (vv4.x * va_s[c+0] + vb_s[c+0] > 1.0f) ? 1.f : 0.f;
    vv4.y = (vv4.y * va_s[c+1] + vb_s[c+1] > 1.0f) ? 1.f : 0.f;
    vv4.z = (vv4.z * va_s[c+2] + vb_s[c+2] > 1.0f) ? 1.f : 0.f;
    vv4.w = (vv4.w * va_s[c+3] + vb_s[c+3] > 1.0f) ? 1.f : 0.f;
    *(float4*)&ks[row][c4 * 4] = kv4;
    *(float4*)&vs[row][c4 * 4] = vv4;
  }
  __syncthreads();

  const int d = t & 63;
  const int dp0 = (t >> 6) * 16;
  float acc[16];
  #pragma unroll
  for (int j = 0; j < 16; ++j) acc[j] = 0.f;

  for (int m = 0; m < 64; ++m) {
    float vv = vs[m][d];
    #pragma unroll
    for (int q4 = 0; q4 < 4; ++q4) {
      float4 kf = *(const float4*)&ks[m][dp0 + q4 * 4];
      acc[q4 * 4 + 0] = fmaf(kf.x, vv, acc[q4 * 4 + 0]);
      acc[q4 * 4 + 1] = fmaf(kf.y, vv, acc[q4 * 4 + 1]);
      acc[q4 * 4 + 2] = fmaf(kf.z, vv, acc[q4 * 4 + 2]);
      acc[q4 * 4 + 3] = fmaf(kf.w, vv, acc[q4 * 4 + 3]);
    }
  }
  float* kvb = KV + ((size_t)(b * HEADS + h)) * HD * HD;
  #pragma unroll
  for (int j = 0; j < 16; ++j)
    atomicAdd(&kvb[(dp0 + j) * HD + d], acc[j]);
}

// ---------------------------------------------------------------------------
// out1 = scale * spike(q) @ KV (unchanged; out1 stays exact 0.125*integers).
// ---------------------------------------------------------------------------
__global__ __launch_bounds__(256) void qkv_kernel(const float* __restrict__ qraw,
                                                  const float* __restrict__ ab,
                                                  const float* __restrict__ KV,
                                                  float* __restrict__ out1)
{
  const int b = blockIdx.z, h = blockIdx.y, rc = blockIdx.x;
  __shared__ float kvs[64][64];
  __shared__ float qs[128][64];
  __shared__ float qa_s[64], qb_s[64];
  const int t = threadIdx.x;

  if (t < 64) {
    float2 qab = ((const float2*)ab)[0 * CDIM + h * HD + t];
    qa_s[t] = qab.x; qb_s[t] = qab.y;
  }
  __syncthreads();

  const float* kvb = KV + ((size_t)(b * HEADS + h)) * HD * HD;
  #pragma unroll
  for (int i = 0; i < 4; ++i) {
    int f = t + i * 256;
    int row = f >> 4, c4 = f & 15;
    *(float4*)&kvs[row][c4 * 4] = *(const float4*)(kvb + row * 64 + c4 * 4);
  }
  const size_t qbase = ((size_t)(b * NSEQ + rc * 128)) * CDIM + h * HD;
  #pragma unroll
  for (int i = 0; i < 8; ++i) {
    int f = t + i * 256;
    int row = f >> 4, c4 = f & 15;
    float4 v = *(const float4*)(qraw + qbase + (size_t)row * CDIM + c4 * 4);
    int c = c4 * 4;
    v.x = (v.x * qa_s[c+0] + qb_s[c+0] > 1.0f) ? 1.f : 0.f;
    v.y = (v.y * qa_s[c+1] + qb_s[c+1] > 1.0f) ? 1.f : 0.f;
    v.z = (v.z * qa_s[c+2] + qb_s[c+2] > 1.0f) ? 1.f : 0.f;
    v.w = (v.w * qa_s[c+3] + qb_s[c+3] > 1.0f) ? 1.f : 0.f;
    *(float4*)&qs[row][c4 * 4] = v;
  }
  __syncthreads();

  const int d = t & 63;
  const int rg = t >> 6;
  for (int r = rg * 32; r < rg * 32 + 32; ++r) {
    float acc = 0.f;
    #pragma unroll
    for (int dq = 0; dq < 16; ++dq) {
      float4 qf = *(const float4*)&qs[r][dq * 4];
      acc = fmaf(qf.x, kvs[dq * 4 + 0][d], acc);
      acc = fmaf(qf.y, kvs[dq * 4 + 1][d], acc);
      acc = fmaf(qf.z, kvs[dq * 4 + 2][d], acc);
      acc = fmaf(qf.w, kvs[dq * 4 + 3][d], acc);
    }
    out1[((size_t)(b * NSEQ + rc * 128 + r)) * CDIM + h * HD + d] = acc * 0.125f;
  }
}

// ---------------------------------------------------------------------------
extern "C" void kernel_launch(void* const* d_in, const int* in_sizes, int n_in,
                              void* d_out, int out_size, void* d_ws, size_t ws_size,
                              hipStream_t stream)
{
  const float* x  = (const float*)d_in[0];
  const float* Wq = (const float*)d_in[1];
  const float* Wk = (const float*)d_in[2];
  const float* Wv = (const float*)d_in[3];
  const float* Wo = (const float*)d_in[4];
  const float* qg = (const float*)d_in[5];
  const float* qb = (const float*)d_in[6];
  const float* kg = (const float*)d_in[7];
  const float* kb = (const float*)d_in[8];
  const float* vg = (const float*)d_in[9];
  const float* vb = (const float*)d_in[10];
  float* out = (float*)d_out;

  char* ws = (char*)d_ws;
  const size_t ybytes  = (size_t)M_ROWS * CDIM * sizeof(float);            // 33.55 MB
  const size_t pbytes  = (size_t)3 * NPART * CDIM * 2 * sizeof(float);     // 3.15 MB
  const size_t abbytes = (size_t)3 * CDIM * 2 * sizeof(float);
  const size_t kvbytes = (size_t)BATCH * HEADS * HD * HD * sizeof(float);  // 2.10 MB
  const size_t need = 3 * ybytes + pbytes + abbytes + kvbytes;             // ~106 MB

  if (ws_size < need) return;   // clean validation failure instead of OOB fault

  float* yq      = (float*)(ws);
  float* yk      = (float*)(ws + ybytes);
  float* yv      = (float*)(ws + 2 * ybytes);
  float* partial = (float*)(ws + 3 * ybytes);
  float* ab      = (float*)(ws + 3 * ybytes + pbytes);
  float* KV      = (float*)(ws + 3 * ybytes + pbytes + abbytes);
  float* out1    = yk;  // safe reuse: k consumed by kv_kernel before qkv writes

  hipMemsetAsync(KV, 0, kvbytes, stream);

  // 1) y{q,k,v} = x @ W{q,k,v}.T   (fp16x2 split MFMA, err ~7e-7)
  gemm16<<<dim3(CDIM / 128, M_ROWS / 128, 3), 256, 0, stream>>>(
      x, Wq, Wk, Wv, yq, yk, yv, CDIM, CDIM);

  // 2) deterministic batch stats (structure bit-identical to passing round)
  stats_partial<<<dim3(NPART / 2, 3), 256, 0, stream>>>(yq, partial);
  finalize_stats<<<3, CDIM, 0, stream>>>(partial, ab, qg, qb, kg, kb, vg, vb);

  // 3) exact-spike fixup for threshold-adjacent samples
  fixup_kernel<<<2048, 256, 0, stream>>>(yq, ab, x, Wq, Wk, Wv);

  // 4) KV = spike(k)^T spike(v)
  kv_kernel<<<dim3(NSEQ / 64, HEADS, BATCH), 256, 0, stream>>>(yk, yv, ab, KV);

  // 5) out1 = scale * spike(q) @ KV  (exact integers * 0.125)
  qkv_kernel<<<dim3(NSEQ / 128, HEADS, BATCH), 256, 0, stream>>>(yq, ab, KV, out1);

  // 6) out = out1 @ Wo.T  (fp16x2 MFMA; out1 split is exact, err ~1e-5 abs)
  gemm16<<<dim3(CDIM / 128, M_ROWS / 128, 1), 256, 0, stream>>>(
      out1, Wo, Wo, Wo, out, out, out, CDIM, CDIM);
}

// Round 9
// 373.762 us; speedup vs baseline: 1.5944x; 1.0137x over previous
//
#include <hip/hip_runtime.h>
#include <hip/hip_bf16.h>
#include <cstdint>
#include <cstddef>

#define M_ROWS 16384   // B*N
#define CDIM   512
#define HEADS  8
#define HD     64
#define NSEQ   1024
#define BATCH  16
#define NPART  256     // deterministic stats partial rows per branch

typedef _Float16 h8 __attribute__((ext_vector_type(8)));
typedef float f4 __attribute__((ext_vector_type(4)));

// Split one f32 into fp16 hi + fp16 lo*2^11 (classic 2-term split; lo pre-scaled
// so it stays in fp16 normal range -> MFMA denorm flush is harmless).
__device__ __forceinline__ void split8(float4 u, float4 v, h8& hi, h8& lo) {
  float t[8] = {u.x, u.y, u.z, u.w, v.x, v.y, v.z, v.w};
  #pragma unroll
  for (int e = 0; e < 8; ++e) {
    _Float16 h = (_Float16)t[e];
    hi[e] = h;
    lo[e] = (_Float16)((t[e] - (float)h) * 2048.0f);
  }
}

// Spike with exact-recompute guard: if the bn-space value sits within 1e-4 of
// the threshold (fp16x2 GEMM err ~2e-6 << band), recompute the exact f32
// serial-k fma dot (bit-identical to the round-5 f32 GEMM, absmax=0) and
// decide on that. Rare (~1.2K of 25M) -> divergence cost ~1 us total.
__device__ __forceinline__ float spike_or_exact(float raw, float a, float b,
                                                const float* __restrict__ xr,
                                                const float* __restrict__ wrow) {
  float t = raw * a + b;
  if (__builtin_expect(fabsf(t - 1.0f) < 1e-4f, 0)) {
    float acc = 0.f;
    for (int k = 0; k < CDIM; ++k) acc = fmaf(xr[k], wrow[k], acc);
    t = acc * a + b;
  }
  return t > 1.0f ? 1.f : 0.f;
}

// ---------------------------------------------------------------------------
// MFMA GEMM: C[m,n] = sum_k A[m,k]*W[n,k] via fp16x2 split precision.
// y = (Ah+Al/2^11)(Wh+Wl/2^11) ~= Ah*Wh + (Ah*Wl2 + Al2*Wh)*2^-11  (3 MFMA)
// 128x128 tile, BK=32, 4 waves of 64x64 (4x4 fragments of 16x16x32).
// LDS: pitch 32 halves (64 B) + XOR swizzle col^=((row>>1)&3)<<3 (halves).
// Phase-audited (8 lanes x 16 B per LDS cycle): staging stores AND fragment
// reads each hit 8 distinct 16B bank-windows -> conflict-free (was 2-way on
// every store phase at 80 B pitch: 1.26e7 conflict cycles = 18% of runtime).
// Arithmetic order identical to the round-8 passing kernel (layout-only).
// ---------------------------------------------------------------------------
__global__ __launch_bounds__(256, 2) void gemm16(
    const float* __restrict__ A,
    const float* __restrict__ W0, const float* __restrict__ W1, const float* __restrict__ W2,
    float* __restrict__ C0, float* __restrict__ C1, float* __restrict__ C2,
    int K, int ldc)
{
  const float* W = (blockIdx.z == 0) ? W0 : (blockIdx.z == 1) ? W1 : W2;
  float* Cm      = (blockIdx.z == 0) ? C0 : (blockIdx.z == 1) ? C1 : C2;

  __shared__ _Float16 sAh[128][32], sAl[128][32], sBh[128][32], sBl[128][32];

  const int tid = threadIdx.x;
  const int bm = blockIdx.y * 128;
  const int bn = blockIdx.x * 128;
  const int srow = tid >> 1;                    // staging row 0..127
  const int scol = (tid & 1) * 16;              // staging col (halves)
  const int sc1  = scol ^ (((srow >> 1) & 3) << 3);  // swizzled col; 2nd = ^8

  const int ln = tid & 63;
  const int wr = ((tid >> 6) >> 1) * 64;        // wave row base
  const int wc = ((tid >> 6) & 1) * 64;         // wave col base
  const int fr = ln & 15;                       // fragment row/col
  const int fk = (ln >> 4) * 8;                 // fragment k offset (halves)

  f4 acc1[4][4], acc2[4][4];
  #pragma unroll
  for (int i = 0; i < 4; ++i)
    #pragma unroll
    for (int j = 0; j < 4; ++j) { acc1[i][j] = 0.f; acc2[i][j] = 0.f; }

  const float* ga = A + (size_t)(bm + srow) * K + scol;
  const float* gb = W + (size_t)(bn + srow) * K + scol;

  // prologue: load K-step 0
  float4 a0 = *(const float4*)(ga + 0),  a1 = *(const float4*)(ga + 4);
  float4 a2 = *(const float4*)(ga + 8),  a3 = *(const float4*)(ga + 12);
  float4 b0 = *(const float4*)(gb + 0),  b1 = *(const float4*)(gb + 4);
  float4 b2 = *(const float4*)(gb + 8),  b3 = *(const float4*)(gb + 12);

  for (int k0 = 0; k0 < K; k0 += 32) {
    h8 hA0, lA0, hA1, lA1, hB0, lB0, hB1, lB1;
    split8(a0, a1, hA0, lA0); split8(a2, a3, hA1, lA1);
    split8(b0, b1, hB0, lB0); split8(b2, b3, hB1, lB1);
    __syncthreads();                      // prior iteration's reads complete
    *(h8*)&sAh[srow][sc1] = hA0; *(h8*)&sAh[srow][sc1 ^ 8] = hA1;
    *(h8*)&sAl[srow][sc1] = lA0; *(h8*)&sAl[srow][sc1 ^ 8] = lA1;
    *(h8*)&sBh[srow][sc1] = hB0; *(h8*)&sBh[srow][sc1 ^ 8] = hB1;
    *(h8*)&sBl[srow][sc1] = lB0; *(h8*)&sBl[srow][sc1 ^ 8] = lB1;
    __syncthreads();

    if (k0 + 32 < K) {                    // prefetch next K-step under MFMA
      const float* pa = ga + k0 + 32;
      a0 = *(const float4*)(pa + 0);  a1 = *(const float4*)(pa + 4);
      a2 = *(const float4*)(pa + 8);  a3 = *(const float4*)(pa + 12);
      const float* pb = gb + k0 + 32;
      b0 = *(const float4*)(pb + 0);  b1 = *(const float4*)(pb + 4);
      b2 = *(const float4*)(pb + 8);  b3 = *(const float4*)(pb + 12);
    }

    h8 bhf[4], blf[4];
    #pragma unroll
    for (int j = 0; j < 4; ++j) {
      const int rowB = wc + j * 16 + fr;
      const int cB = fk ^ (((rowB >> 1) & 3) << 3);
      bhf[j] = *(const h8*)&sBh[rowB][cB];
      blf[j] = *(const h8*)&sBl[rowB][cB];
    }
    #pragma unroll
    for (int i = 0; i < 4; ++i) {
      const int rowA = wr + i * 16 + fr;
      const int cA = fk ^ (((rowA >> 1) & 3) << 3);
      h8 ah = *(const h8*)&sAh[rowA][cA];
      h8 al = *(const h8*)&sAl[rowA][cA];
      #pragma unroll
      for (int j = 0; j < 4; ++j) {
        acc1[i][j] = __builtin_amdgcn_mfma_f32_16x16x32_f16(ah, bhf[j], acc1[i][j], 0, 0, 0);
        acc2[i][j] = __builtin_amdgcn_mfma_f32_16x16x32_f16(ah, blf[j], acc2[i][j], 0, 0, 0);
        acc2[i][j] = __builtin_amdgcn_mfma_f32_16x16x32_f16(al, bhf[j], acc2[i][j], 0, 0, 0);
      }
    }
  }

  // C/D layout [m89-verified]: col = lane&15, row = (lane>>4)*4 + reg
  const int orow = (ln >> 4) * 4;
  #pragma unroll
  for (int i = 0; i < 4; ++i)
    #pragma unroll
    for (int j = 0; j < 4; ++j) {
      float* cp = Cm + (size_t)(bm + wr + i * 16 + orow) * ldc + (bn + wc + j * 16 + fr);
      #pragma unroll
      for (int r = 0; r < 4; ++r)
        cp[(size_t)r * ldc] = acc1[i][j][r] + acc2[i][j][r] * 4.8828125e-4f;  // 2^-11
    }
}

// ---------------------------------------------------------------------------
// Deterministic batch stats, stage A — BYTE-IDENTICAL to the passing round.
// ---------------------------------------------------------------------------
__global__ __launch_bounds__(256) void stats_partial(const float* __restrict__ y,
                                                     float* __restrict__ partial)
{
  const int branch = blockIdx.y;
  const int chunk = blockIdx.x;
  const int t = threadIdx.x;
  const int sub = t >> 7;          // 0/1: rows [0,64) / [64,128) of the chunk
  const int c4 = t & 127;          // channel group: c4*4 .. c4*4+3
  const float* yb = y + (size_t)branch * M_ROWS * CDIM
                      + (size_t)(chunk * 128 + sub * 64) * CDIM + c4 * 4;

  float s[4] = {0.f, 0.f, 0.f, 0.f}, q[4] = {0.f, 0.f, 0.f, 0.f};
  for (int r = 0; r < 64; ++r) {
    float4 v = *(const float4*)(yb + (size_t)r * CDIM);
    s[0] += v.x; q[0] += v.x * v.x;
    s[1] += v.y; q[1] += v.y * v.y;
    s[2] += v.z; q[2] += v.z * v.z;
    s[3] += v.w; q[3] += v.w * v.w;
  }
  const int pr = chunk * 2 + sub;  // [0, NPART)
  float2* pb = (float2*)partial + ((size_t)branch * NPART + pr) * CDIM + c4 * 4;
  #pragma unroll
  for (int j = 0; j < 4; ++j) pb[j] = make_float2(s[j], q[j]);
}

// ---------------------------------------------------------------------------
// Stage B + affine (unchanged): ab = (gamma*rsig, beta - gamma*mean*rsig).
// ---------------------------------------------------------------------------
__global__ void finalize_stats(const float* __restrict__ partial, float* __restrict__ ab,
                               const float* __restrict__ g0, const float* __restrict__ b0,
                               const float* __restrict__ g1, const float* __restrict__ b1,
                               const float* __restrict__ g2, const float* __restrict__ b2)
{
  const int branch = blockIdx.x;
  const int c = threadIdx.x;  // 512
  const float* g  = branch == 0 ? g0 : branch == 1 ? g1 : g2;
  const float* be = branch == 0 ? b0 : branch == 1 ? b1 : b2;

  float sum = 0.f, sq = 0.f;
  const float2* pb = (const float2*)partial + (size_t)branch * NPART * CDIM + c;
  for (int pr = 0; pr < NPART; ++pr) {
    float2 v = pb[(size_t)pr * CDIM];
    sum += v.x; sq += v.y;
  }
  const float invn = 1.f / (float)M_ROWS;
  float mean = sum * invn;
  float var  = sq * invn - mean * mean;   // biased variance (matches reference)
  float rsig = rsqrtf(var + 1e-5f);
  ((float2*)ab)[branch * CDIM + c] = make_float2(g[c] * rsig, be[c] - g[c] * mean * rsig);
}

// ---------------------------------------------------------------------------
// KV = spike(k)^T spike(v) per (b,h); spikes inline with exact-recompute guard
// (replaces the separate fixup pass: same raw-y check, same serial-fma dot ->
// identical spike decisions, one fewer 100MB pass).
// ---------------------------------------------------------------------------
__global__ __launch_bounds__(256) void kv_kernel(const float* __restrict__ kraw,
                                                 const float* __restrict__ vraw,
                                                 const float* __restrict__ ab,
                                                 const float* __restrict__ x,
                                                 const float* __restrict__ Wk,
                                                 const float* __restrict__ Wv,
                                                 float* __restrict__ KV)
{
  const int b = blockIdx.z, h = blockIdx.y, mc = blockIdx.x;
  __shared__ float ks[64][64];
  __shared__ float vs[64][64];
  __shared__ float ka_s[64], kb_s[64], va_s[64], vb_s[64];
  const int t = threadIdx.x;

  if (t < 64) {
    float2 kab = ((const float2*)ab)[1 * CDIM + h * HD + t];
    ka_s[t] = kab.x; kb_s[t] = kab.y;
  } else if (t < 128) {
    int j = t - 64;
    float2 vab = ((const float2*)ab)[2 * CDIM + h * HD + j];
    va_s[j] = vab.x; vb_s[j] = vab.y;
  }
  __syncthreads();

  const size_t base = ((size_t)(b * NSEQ + mc * 64)) * CDIM + h * HD;
  #pragma unroll
  for (int i = 0; i < 4; ++i) {
    int f = t + i * 256;          // 1024 float4 per matrix
    int row = f >> 4, c4 = f & 15;
    float4 kv4 = *(const float4*)(kraw + base + (size_t)row * CDIM + c4 * 4);
    float4 vv4 = *(const float4*)(vraw + base + (size_t)row * CDIM + c4 * 4);
    int c = c4 * 4;
    const float* xr = x + (size_t)(b * NSEQ + mc * 64 + row) * CDIM;
    const float* wk0 = Wk + (size_t)(h * HD + c) * CDIM;
    const float* wv0 = Wv + (size_t)(h * HD + c) * CDIM;
    kv4.x = spike_or_exact(kv4.x, ka_s[c+0], kb_s[c+0], xr, wk0);
    kv4.y = spike_or_exact(kv4.y, ka_s[c+1], kb_s[c+1], xr, wk0 + CDIM);
    kv4.z = spike_or_exact(kv4.z, ka_s[c+2], kb_s[c+2], xr, wk0 + 2 * CDIM);
    kv4.w = spike_or_exact(kv4.w, ka_s[c+3], kb_s[c+3], xr, wk0 + 3 * CDIM);
    vv4.x = spike_or_exact(vv4.x, va_s[c+0], vb_s[c+0], xr, wv0);
    vv4.y = spike_or_exact(vv4.y, va_s[c+1], vb_s[c+1], xr, wv0 + CDIM);
    vv4.z = spike_or_exact(vv4.z, va_s[c+2], vb_s[c+2], xr, wv0 + 2 * CDIM);
    vv4.w = spike_or_exact(vv4.w, va_s[c+3], vb_s[c+3], xr, wv0 + 3 * CDIM);
    *(float4*)&ks[row][c4 * 4] = kv4;
    *(float4*)&vs[row][c4 * 4] = vv4;
  }
  __syncthreads();

  const int d = t & 63;
  const int dp0 = (t >> 6) * 16;
  float acc[16];
  #pragma unroll
  for (int j = 0; j < 16; ++j) acc[j] = 0.f;

  for (int m = 0; m < 64; ++m) {
    float vv = vs[m][d];
    #pragma unroll
    for (int q4 = 0; q4 < 4; ++q4) {
      float4 kf = *(const float4*)&ks[m][dp0 + q4 * 4];
      acc[q4 * 4 + 0] = fmaf(kf.x, vv, acc[q4 * 4 + 0]);
      acc[q4 * 4 + 1] = fmaf(kf.y, vv, acc[q4 * 4 + 1]);
      acc[q4 * 4 + 2] = fmaf(kf.z, vv, acc[q4 * 4 + 2]);
      acc[q4 * 4 + 3] = fmaf(kf.w, vv, acc[q4 * 4 + 3]);
    }
  }
  float* kvb = KV + ((size_t)(b * HEADS + h)) * HD * HD;
  #pragma unroll
  for (int j = 0; j < 16; ++j)
    atomicAdd(&kvb[(dp0 + j) * HD + d], acc[j]);
}

// ---------------------------------------------------------------------------
// out1 = scale * spike(q) @ KV; q spike inline with exact-recompute guard.
// ---------------------------------------------------------------------------
__global__ __launch_bounds__(256) void qkv_kernel(const float* __restrict__ qraw,
                                                  const float* __restrict__ ab,
                                                  const float* __restrict__ KV,
                                                  const float* __restrict__ x,
                                                  const float* __restrict__ Wq,
                                                  float* __restrict__ out1)
{
  const int b = blockIdx.z, h = blockIdx.y, rc = blockIdx.x;
  __shared__ float kvs[64][64];
  __shared__ float qs[128][64];
  __shared__ float qa_s[64], qb_s[64];
  const int t = threadIdx.x;

  if (t < 64) {
    float2 qab = ((const float2*)ab)[0 * CDIM + h * HD + t];
    qa_s[t] = qab.x; qb_s[t] = qab.y;
  }
  __syncthreads();

  const float* kvb = KV + ((size_t)(b * HEADS + h)) * HD * HD;
  #pragma unroll
  for (int i = 0; i < 4; ++i) {
    int f = t + i * 256;
    int row = f >> 4, c4 = f & 15;
    *(float4*)&kvs[row][c4 * 4] = *(const float4*)(kvb + row * 64 + c4 * 4);
  }
  const size_t qbase = ((size_t)(b * NSEQ + rc * 128)) * CDIM + h * HD;
  #pragma unroll
  for (int i = 0; i < 8; ++i) {
    int f = t + i * 256;
    int row = f >> 4, c4 = f & 15;
    float4 v = *(const float4*)(qraw + qbase + (size_t)row * CDIM + c4 * 4);
    int c = c4 * 4;
    const float* xr = x + (size_t)(b * NSEQ + rc * 128 + row) * CDIM;
    const float* wq0 = Wq + (size_t)(h * HD + c) * CDIM;
    v.x = spike_or_exact(v.x, qa_s[c+0], qb_s[c+0], xr, wq0);
    v.y = spike_or_exact(v.y, qa_s[c+1], qb_s[c+1], xr, wq0 + CDIM);
    v.z = spike_or_exact(v.z, qa_s[c+2], qb_s[c+2], xr, wq0 + 2 * CDIM);
    v.w = spike_or_exact(v.w, qa_s[c+3], qb_s[c+3], xr, wq0 + 3 * CDIM);
    *(float4*)&qs[row][c4 * 4] = v;
  }
  __syncthreads();

  const int d = t & 63;
  const int rg = t >> 6;
  for (int r = rg * 32; r < rg * 32 + 32; ++r) {
    float acc = 0.f;
    #pragma unroll
    for (int dq = 0; dq < 16; ++dq) {
      float4 qf = *(const float4*)&qs[r][dq * 4];
      acc = fmaf(qf.x, kvs[dq * 4 + 0][d], acc);
      acc = fmaf(qf.y, kvs[dq * 4 + 1][d], acc);
      acc = fmaf(qf.z, kvs[dq * 4 + 2][d], acc);
      acc = fmaf(qf.w, kvs[dq * 4 + 3][d], acc);
    }
    out1[((size_t)(b * NSEQ + rc * 128 + r)) * CDIM + h * HD + d] = acc * 0.125f;
  }
}

// ---------------------------------------------------------------------------
extern "C" void kernel_launch(void* const* d_in, const int* in_sizes, int n_in,
                              void* d_out, int out_size, void* d_ws, size_t ws_size,
                              hipStream_t stream)
{
  const float* x  = (const float*)d_in[0];
  const float* Wq = (const float*)d_in[1];
  const float* Wk = (const float*)d_in[2];
  const float* Wv = (const float*)d_in[3];
  const float* Wo = (const float*)d_in[4];
  const float* qg = (const float*)d_in[5];
  const float* qb = (const float*)d_in[6];
  const float* kg = (const float*)d_in[7];
  const float* kb = (const float*)d_in[8];
  const float* vg = (const float*)d_in[9];
  const float* vb = (const float*)d_in[10];
  float* out = (float*)d_out;

  char* ws = (char*)d_ws;
  const size_t ybytes  = (size_t)M_ROWS * CDIM * sizeof(float);            // 33.55 MB
  const size_t pbytes  = (size_t)3 * NPART * CDIM * 2 * sizeof(float);     // 3.15 MB
  const size_t abbytes = (size_t)3 * CDIM * 2 * sizeof(float);
  const size_t kvbytes = (size_t)BATCH * HEADS * HD * HD * sizeof(float);  // 2.10 MB
  const size_t need = 3 * ybytes + pbytes + abbytes + kvbytes;             // ~106 MB

  if (ws_size < need) return;   // clean validation failure instead of OOB fault

  float* yq      = (float*)(ws);
  float* yk      = (float*)(ws + ybytes);
  float* yv      = (float*)(ws + 2 * ybytes);
  float* partial = (float*)(ws + 3 * ybytes);
  float* ab      = (float*)(ws + 3 * ybytes + pbytes);
  float* KV      = (float*)(ws + 3 * ybytes + pbytes + abbytes);
  float* out1    = yk;  // safe reuse: k consumed by kv_kernel before qkv writes

  hipMemsetAsync(KV, 0, kvbytes, stream);

  // 1) y{q,k,v} = x @ W{q,k,v}.T   (fp16x2 split MFMA, err ~2e-6)
  gemm16<<<dim3(CDIM / 128, M_ROWS / 128, 3), 256, 0, stream>>>(
      x, Wq, Wk, Wv, yq, yk, yv, CDIM, CDIM);

  // 2) deterministic batch stats (bit-identical structure to passing rounds)
  stats_partial<<<dim3(NPART / 2, 3), 256, 0, stream>>>(yq, partial);
  finalize_stats<<<3, CDIM, 0, stream>>>(partial, ab, qg, qb, kg, kb, vg, vb);

  // 3) KV = spike(k)^T spike(v), spikes inline w/ exact-recompute guard
  kv_kernel<<<dim3(NSEQ / 64, HEADS, BATCH), 256, 0, stream>>>(
      yk, yv, ab, x, Wk, Wv, KV);

  // 4) out1 = scale * spike(q) @ KV, spike inline w/ exact-recompute guard
  qkv_kernel<<<dim3(NSEQ / 128, HEADS, BATCH), 256, 0, stream>>>(
      yq, ab, KV, x, Wq, out1);

  // 5) out = out1 @ Wo.T  (fp16x2 MFMA; out1 split is exact, err ~1e-5 abs)
  gemm16<<<dim3(CDIM / 128, M_ROWS / 128, 1), 256, 0, stream>>>(
      out1, Wo, Wo, Wo, out, out, out, CDIM, CDIM);
}